// Round 1
// baseline (214.695 us; speedup 1.0000x reference)
//
#include <hip/hip_runtime.h>

typedef __bf16 bf16x8 __attribute__((ext_vector_type(8)));
typedef __bf16 bf16x4v __attribute__((ext_vector_type(4)));
typedef float f32x4 __attribute__((ext_vector_type(4)));

typedef const void __attribute__((address_space(1)))* gas_ptr;
typedef void __attribute__((address_space(3)))* las_ptr;

#define DEVFN __device__ __forceinline__

DEVFN void gload16(const __bf16* g, __bf16* lds) {
  __builtin_amdgcn_global_load_lds((gas_ptr)g, (las_ptr)lds, 16, 0, 0);
}

// ---------------------------------------------------------------------------
// cast fp32 -> bf16, 4 elems/thread
__global__ __launch_bounds__(256) void cast_k(const float* __restrict__ in,
                                              __bf16* __restrict__ out, int n4) {
  int i = blockIdx.x * 256 + threadIdx.x;
  if (i >= n4) return;
  float4 v = ((const float4*)in)[i];
  bf16x4v o = { (__bf16)v.x, (__bf16)v.y, (__bf16)v.z, (__bf16)v.w };
  ((bf16x4v*)out)[i] = o;
}

// ---------------------------------------------------------------------------
// V[b][s][c] -> Vt[b][c][s]
__global__ void transpose_k(const __bf16* __restrict__ V, __bf16* __restrict__ Vt,
                            int T, int C) {
  __shared__ __bf16 tile[32][33];
  int b = blockIdx.z;
  int s0 = blockIdx.x * 32, c0 = blockIdx.y * 32;
  const __bf16* Vb = V + (size_t)b * T * C;
  __bf16* Vtb = Vt + (size_t)b * C * T;
  int tx = threadIdx.x, ty = threadIdx.y;  // 32 x 8
  for (int i = ty; i < 32; i += 8) tile[i][tx] = Vb[(size_t)(s0 + i) * C + c0 + tx];
  __syncthreads();
  for (int i = ty; i < 32; i += 8) Vtb[(size_t)(c0 + i) * T + s0 + tx] = tile[tx][i];
}

// ---------------------------------------------------------------------------
// causal row softmax, in-place: fp32 scores row -> bf16 attn row (same base,
// bf16 row occupies first half of the fp32 row's bytes; stride 2T bf16 elems)
__global__ __launch_bounds__(256) void softmax_causal_k(float* __restrict__ scores, int T) {
  const int row = blockIdx.x;      // b*T + t
  const int t = row & (T - 1);
  float* srow = scores + (size_t)row * T;
  __bf16* arow = (__bf16*)srow;
  __shared__ float rb[2048];
  __shared__ float redmax[4];
  __shared__ float redsum[4];
  const int tid = threadIdx.x, lane = tid & 63, wave = tid >> 6;
  for (int s = tid; s < T; s += 256) rb[s] = (s <= t) ? srow[s] : -3.0e38f;
  __syncthreads();
  float lmax = -3.0e38f;
  for (int s = tid; s < T; s += 256) lmax = fmaxf(lmax, rb[s]);
#pragma unroll
  for (int off = 32; off; off >>= 1) lmax = fmaxf(lmax, __shfl_down(lmax, off));
  if (lane == 0) redmax[wave] = lmax;
  __syncthreads();
  float gmax = fmaxf(fmaxf(redmax[0], redmax[1]), fmaxf(redmax[2], redmax[3]));
  float lsum = 0.f;
  for (int s = tid; s < T; s += 256) {
    float e = (s <= t) ? __expf(rb[s] - gmax) : 0.f;
    rb[s] = e;
    lsum += e;
  }
#pragma unroll
  for (int off = 32; off; off >>= 1) lsum += __shfl_down(lsum, off);
  if (lane == 0) redsum[wave] = lsum;
  __syncthreads();
  float inv = 1.f / (redsum[0] + redsum[1] + redsum[2] + redsum[3]);
  for (int s = tid; s < T; s += 256) arow[s] = (__bf16)(rb[s] * inv);
}

// ---------------------------------------------------------------------------
// NT GEMM: C[m,n] = sum_k A[m,k]*B[n,k].  128x128 tile, BK=32, 4 waves,
// double-buffered LDS, global_load_lds width-16 staging, 2-phase pipeline.
// MODE 0: proj  -> bf16 out + bias[z]        (z selects W slot / out slot)
// MODE 1: scores-> f32 out * scale, skip blocks with by>bx (z = batch)
// MODE 2: PV    -> f32 out, k-tiles limited to causal range (z = batch)
template <int MODE>
__global__ __launch_bounds__(256) void gemm_nt(
    const __bf16* __restrict__ A, const __bf16* __restrict__ B, void* __restrict__ Out,
    int lda, int ldb, int ldo, int nkt_full,
    const float* __restrict__ bias0, const float* __restrict__ bias1,
    const float* __restrict__ bias2, float scale,
    size_t strideA_z, size_t strideB_z, size_t strideO_z) {
  if (MODE == 1 && blockIdx.y > blockIdx.x) return;  // fully-masked tile
  const int z = blockIdx.z;
  A += (size_t)z * strideA_z;
  B += (size_t)z * strideB_z;
  const int m0 = blockIdx.x * 128;
  const int n0 = blockIdx.y * 128;
  int nkt = nkt_full;
  if (MODE == 2) nkt = min(nkt, (int)(blockIdx.x + 1) * 4);  // causal k-limit (BK=32)

  __shared__ __align__(16) __bf16 smA[2][128 * 32];
  __shared__ __align__(16) __bf16 smB[2][128 * 32];

  const int tid = threadIdx.x;
  const int lane = tid & 63;
  const int wave = tid >> 6;
  const int r_in = lane >> 2;         // 0..15 (row within 16-row chunk)
  const int c8 = (lane & 3) * 8;      // k-offset in elements

  const __bf16* Ab = A + (size_t)m0 * lda;
  const __bf16* Bb = B + (size_t)n0 * ldb;

  auto stage = [&](int buf, int kt) {
    const int kofs = kt * 32 + c8;
#pragma unroll
    for (int rr = 0; rr < 2; ++rr) {
      int row = rr * 64 + wave * 16 + r_in;
      int chunk = (rr * 64 + wave * 16) * 32;  // wave-uniform LDS base (elems)
      gload16(Ab + (size_t)row * lda + kofs, &smA[buf][chunk]);
      gload16(Bb + (size_t)row * ldb + kofs, &smB[buf][chunk]);
    }
  };

  f32x4 acc[4][4];
  const f32x4 zero = {0.f, 0.f, 0.f, 0.f};
#pragma unroll
  for (int m = 0; m < 4; ++m)
#pragma unroll
    for (int n = 0; n < 4; ++n) acc[m][n] = zero;

  const int wr = (wave >> 1) * 64;  // wave's 64x64 sub-tile
  const int wc = (wave & 1) * 64;
  const int lr = lane & 15;
  const int kg = lane >> 4;

  stage(0, 0);
  __syncthreads();  // compiler drains vmcnt before barrier
  int cur = 0;
  for (int kt = 0; kt < nkt; ++kt) {
    if (kt + 1 < nkt) stage(cur ^ 1, kt + 1);  // prefetch next tile
    bf16x8 af[4], bfr[4];
#pragma unroll
    for (int m = 0; m < 4; ++m)
      af[m] = *(const bf16x8*)&smA[cur][(wr + m * 16 + lr) * 32 + kg * 8];
#pragma unroll
    for (int n = 0; n < 4; ++n)
      bfr[n] = *(const bf16x8*)&smB[cur][(wc + n * 16 + lr) * 32 + kg * 8];
#pragma unroll
    for (int m = 0; m < 4; ++m)
#pragma unroll
      for (int n = 0; n < 4; ++n)
        acc[m][n] = __builtin_amdgcn_mfma_f32_16x16x32_bf16(af[m], bfr[n], acc[m][n], 0, 0, 0);
    __syncthreads();  // also waits prefetch (vmcnt 0) -> next buf ready
    cur ^= 1;
  }

  // epilogue: D row=(lane>>4)*4+i, col=lane&15 within each 16x16 fragment
#pragma unroll
  for (int m = 0; m < 4; ++m) {
#pragma unroll
    for (int i = 0; i < 4; ++i) {
      int r = m0 + wr + m * 16 + kg * 4 + i;
#pragma unroll
      for (int n = 0; n < 4; ++n) {
        int c = n0 + wc + n * 16 + lr;
        float v = acc[m][n][i];
        if (MODE == 0) {
          const float* bias = (z == 0) ? bias0 : (z == 1) ? bias1 : bias2;
          ((__bf16*)Out)[(size_t)z * strideO_z + (size_t)r * ldo + c] = (__bf16)(v + bias[c]);
        } else if (MODE == 1) {
          ((float*)Out)[(size_t)z * strideO_z + (size_t)r * ldo + c] = v * scale;
        } else {
          ((float*)Out)[(size_t)z * strideO_z + (size_t)r * ldo + c] = v;
        }
      }
    }
  }
}

// ---------------------------------------------------------------------------
extern "C" void kernel_launch(void* const* d_in, const int* in_sizes, int n_in,
                              void* d_out, int out_size, void* d_ws, size_t ws_size,
                              hipStream_t stream) {
  const float* x  = (const float*)d_in[0];
  const float* Wk = (const float*)d_in[1];
  const float* Wq = (const float*)d_in[2];
  const float* Wv = (const float*)d_in[3];
  const float* bk = (const float*)d_in[4];
  const float* bq = (const float*)d_in[5];
  const float* bv = (const float*)d_in[6];
  float* out = (float*)d_out;

  const int B = 4, T = 2048, C = 1024;
  const int M = B * T;  // 8192

  char* ws = (char*)d_ws;
  __bf16* x_bf = (__bf16*)ws;                    // 8,388,608 el  (16 MB)
  __bf16* w_bf = (__bf16*)(ws + 16777216);       // 3x1,048,576  (6 MB)
  __bf16* kqv  = (__bf16*)(ws + 23068672);       // 3x8,388,608  (48 MB)
  __bf16* vt   = (__bf16*)(ws + 73400320);       // 8,388,608    (16 MB)
  float*  sc   = (float*)(ws + 90177536);        // 16,777,216 f32 (64 MB); attn aliased bf16

  // casts
  cast_k<<<(M * C / 4 + 255) / 256, 256, 0, stream>>>(x, x_bf, M * C / 4);
  cast_k<<<(C * C / 4 + 255) / 256, 256, 0, stream>>>(Wk, w_bf, C * C / 4);
  cast_k<<<(C * C / 4 + 255) / 256, 256, 0, stream>>>(Wq, w_bf + C * C, C * C / 4);
  cast_k<<<(C * C / 4 + 255) / 256, 256, 0, stream>>>(Wv, w_bf + 2 * C * C, C * C / 4);

  // QKV projection: [8192,1024] x [1024,1024]^T, z = {K,Q,V}
  gemm_nt<0><<<dim3(M / 128, C / 128, 3), 256, 0, stream>>>(
      x_bf, w_bf, kqv, C, C, C, C / 32, bk, bq, bv, 1.f,
      (size_t)0, (size_t)C * C, (size_t)M * C);

  // V transpose -> Vt[b][c][s]
  transpose_k<<<dim3(T / 32, C / 32, B), dim3(32, 8), 0, stream>>>(
      kqv + 2 * (size_t)M * C, vt, T, C);

  // scores = K @ Q^T / sqrt(C), per batch; skip upper-triangle blocks
  gemm_nt<1><<<dim3(T / 128, T / 128, B), 256, 0, stream>>>(
      kqv, kqv + (size_t)M * C, sc, C, C, T, C / 32, nullptr, nullptr, nullptr,
      0.03125f, (size_t)T * C, (size_t)T * C, (size_t)T * T);

  // causal softmax, scores(f32) -> attn(bf16) in place
  softmax_causal_k<<<B * T, 256, 0, stream>>>(sc, T);

  // out = attn @ V  (attn bf16 rows, stride 2T; B = Vt[n=c][k=s])
  gemm_nt<2><<<dim3(T / 128, C / 128, B), 256, 0, stream>>>(
      (const __bf16*)sc, vt, out, 2 * T, T, C, T / 32, nullptr, nullptr, nullptr,
      1.f, (size_t)T * 2 * T, (size_t)C * T, (size_t)T * C);
}

// Round 2
// 214.335 us; speedup vs baseline: 1.0017x; 1.0017x over previous
//
#include <hip/hip_runtime.h>

typedef __bf16 bf16x8 __attribute__((ext_vector_type(8)));
typedef __bf16 bf16x4v __attribute__((ext_vector_type(4)));
typedef float f32x4 __attribute__((ext_vector_type(4)));

typedef const void __attribute__((address_space(1)))* gas_ptr;
typedef void __attribute__((address_space(3)))* las_ptr;

#define MEMFENCE asm volatile("" ::: "memory")

__device__ __forceinline__ void gload16(const __bf16* g, __bf16* lds) {
  __builtin_amdgcn_global_load_lds((gas_ptr)g, (las_ptr)lds, 16, 0, 0);
}

// ---------------------------------------------------------------------------
// cast fp32 -> bf16, 4 elems/thread
__global__ __launch_bounds__(256) void cast_k(const float* __restrict__ in,
                                              __bf16* __restrict__ out, int n4) {
  int i = blockIdx.x * 256 + threadIdx.x;
  if (i >= n4) return;
  float4 v = ((const float4*)in)[i];
  bf16x4v o = { (__bf16)v.x, (__bf16)v.y, (__bf16)v.z, (__bf16)v.w };
  ((bf16x4v*)out)[i] = o;
}

// ---------------------------------------------------------------------------
// V[b][s][c] -> Vt[b][c][s]
__global__ void transpose_k(const __bf16* __restrict__ V, __bf16* __restrict__ Vt,
                            int T, int C) {
  __shared__ __bf16 tile[32][33];
  int b = blockIdx.z;
  int s0 = blockIdx.x * 32, c0 = blockIdx.y * 32;
  const __bf16* Vb = V + (size_t)b * T * C;
  __bf16* Vtb = Vt + (size_t)b * C * T;
  int tx = threadIdx.x, ty = threadIdx.y;  // 32 x 8
  for (int i = ty; i < 32; i += 8) tile[i][tx] = Vb[(size_t)(s0 + i) * C + c0 + tx];
  __syncthreads();
  for (int i = ty; i < 32; i += 8) Vtb[(size_t)(c0 + i) * T + s0 + tx] = tile[tx][i];
}

// ---------------------------------------------------------------------------
// causal row softmax, in-place: fp32 scores row -> bf16 attn row
__global__ __launch_bounds__(256) void softmax_causal_k(float* __restrict__ scores, int T) {
  const int row = blockIdx.x;      // b*T + t
  const int t = row & (T - 1);
  float* srow = scores + (size_t)row * T;
  __bf16* arow = (__bf16*)srow;
  __shared__ float rb[2048];
  __shared__ float redmax[4];
  __shared__ float redsum[4];
  const int tid = threadIdx.x, lane = tid & 63, wave = tid >> 6;
  for (int s = tid; s < T; s += 256) rb[s] = (s <= t) ? srow[s] : -3.0e38f;
  __syncthreads();
  float lmax = -3.0e38f;
  for (int s = tid; s < T; s += 256) lmax = fmaxf(lmax, rb[s]);
#pragma unroll
  for (int off = 32; off; off >>= 1) lmax = fmaxf(lmax, __shfl_down(lmax, off));
  if (lane == 0) redmax[wave] = lmax;
  __syncthreads();
  float gmax = fmaxf(fmaxf(redmax[0], redmax[1]), fmaxf(redmax[2], redmax[3]));
  float lsum = 0.f;
  for (int s = tid; s < T; s += 256) {
    float e = (s <= t) ? __expf(rb[s] - gmax) : 0.f;
    rb[s] = e;
    lsum += e;
  }
#pragma unroll
  for (int off = 32; off; off >>= 1) lsum += __shfl_down(lsum, off);
  if (lane == 0) redsum[wave] = lsum;
  __syncthreads();
  float inv = 1.f / (redsum[0] + redsum[1] + redsum[2] + redsum[3]);
  for (int s = tid; s < T; s += 256) arow[s] = (__bf16)(rb[s] * inv);
}

// ---------------------------------------------------------------------------
// Deep-pipelined NT GEMM: C[m,n] = sum_k A[m,k]*B[n,k].
// Block tile 256x128, BK=64 (2 k-step phases of 16 MFMA), 8 waves (4M x 2N),
// per-wave 64x64 (acc[4][4]). LDS 96 KiB: 2 buf x 2 khalf x {A 256x32, B 128x32}.
// Counted vmcnt (6/3/0), raw s_barrier, lgkmcnt(0)+sched_barrier, setprio.
// XOR swizzle on 16B k-chunks: chunk ^= (row>>1)&3, applied both at the
// pre-swizzled global_load_lds source and at the ds_read_b128 address.
// MODE 0: proj  -> bf16 out + bias[z]
// MODE 1: scores-> f32 out * scale, skip blocks with n0 > m0+255
// MODE 2: PV    -> f32 out, k-tiles limited to causal range
template <int MODE>
__global__ __launch_bounds__(512, 2) void gemm_pipe(
    const __bf16* __restrict__ A, const __bf16* __restrict__ B, void* __restrict__ Out,
    int lda, int ldb, int ldo, int nkt_in,
    const float* __restrict__ bias0, const float* __restrict__ bias1,
    const float* __restrict__ bias2, float scale,
    size_t sAz, size_t sBz, size_t sOz) {
  const int bx = blockIdx.x, by = blockIdx.y, z = blockIdx.z;
  if (MODE == 1 && by > 2 * bx + 1) return;  // fully-masked tile
  A += (size_t)z * sAz;
  B += (size_t)z * sBz;
  const int m0 = bx * 256, n0 = by * 128;
  int nkt = nkt_in;
  if (MODE == 2) nkt = min(nkt, bx * 4 + 4);  // causal k-limit (BK=64)

  __shared__ __align__(16) __bf16 sA[2][2][256 * 32];  // 64 KiB
  __shared__ __align__(16) __bf16 sB[2][2][128 * 32];  // 32 KiB

  const int tid = threadIdx.x;
  const int wid = tid >> 6, lane = tid & 63;
  const int lr = lane & 15, kg = lane >> 4;
  const int wm = wid & 3, wn = wid >> 2;
  const int l4 = lane >> 2, c4 = lane & 3;
  const int swzs = (lane >> 3) & 3;      // staging swizzle term = (lrow>>1)&3
  const int rsw = (lr >> 1) & 3;         // read swizzle term
  const int kofs = ((kg ^ rsw) << 3);    // swizzled elem offset within 32-k row

  const __bf16* Ab = A + (size_t)m0 * lda;
  const __bf16* Bb = B + (size_t)n0 * ldb;

  auto stageA = [&](int buf, int kt, int kh) {  // 2 vmem insts
#pragma unroll
    for (int rnd = 0; rnd < 2; ++rnd) {
      int lrow = rnd * 128 + wid * 16 + l4;
      int gk = kt * 64 + kh * 32 + ((c4 ^ swzs) << 3);
      gload16(Ab + (size_t)lrow * lda + gk, &sA[buf][kh][(rnd * 128 + wid * 16) * 32]);
    }
  };
  auto stageB = [&](int buf, int kt, int kh) {  // 1 vmem inst
    int lrow = wid * 16 + l4;
    int gk = kt * 64 + kh * 32 + ((c4 ^ swzs) << 3);
    gload16(Bb + (size_t)lrow * ldb + gk, &sB[buf][kh][(wid * 16) * 32]);
  };

  f32x4 acc[4][4];
  const f32x4 zero = {0.f, 0.f, 0.f, 0.f};
#pragma unroll
  for (int m = 0; m < 4; ++m)
#pragma unroll
    for (int n = 0; n < 4; ++n) acc[m][n] = zero;

  // prologue: uA0(0) uB0(0) uA1(0) uB1(0) uA0(1) uB0(1)  (9 vmem insts)
  stageA(0, 0, 0); stageB(0, 0, 0);
  stageA(0, 0, 1); stageB(0, 0, 1);
  stageA(1, 1, 0); stageB(1, 1, 0);
  asm volatile("s_waitcnt vmcnt(6)" ::: "memory");
  __builtin_amdgcn_s_barrier();
  MEMFENCE;

  for (int t = 0; t < nkt; ++t) {
    const int buf = t & 1;
    // ---------------- phase 0: k-half 0 ----------------
    bf16x8 af[4], bv[4];
#pragma unroll
    for (int m = 0; m < 4; ++m)
      af[m] = *(const bf16x8*)&sA[buf][0][(wm * 64 + m * 16 + lr) * 32 + kofs];
#pragma unroll
    for (int n = 0; n < 4; ++n)
      bv[n] = *(const bf16x8*)&sB[buf][0][(wn * 64 + n * 16 + lr) * 32 + kofs];
    if (t + 1 < nkt) {                      // stage k-half1 of tile t+1 -> other buf
      stageA(buf ^ 1, t + 1, 1);
      stageB(buf ^ 1, t + 1, 1);
      asm volatile("s_waitcnt vmcnt(6)" ::: "memory");
    } else {
      asm volatile("s_waitcnt vmcnt(0)" ::: "memory");
    }
    __builtin_amdgcn_s_barrier();
    asm volatile("s_waitcnt lgkmcnt(0)" ::: "memory");
    __builtin_amdgcn_sched_barrier(0);
    __builtin_amdgcn_s_setprio(1);
#pragma unroll
    for (int m = 0; m < 4; ++m)
#pragma unroll
      for (int n = 0; n < 4; ++n)
        acc[m][n] = __builtin_amdgcn_mfma_f32_16x16x32_bf16(af[m], bv[n], acc[m][n], 0, 0, 0);
    __builtin_amdgcn_s_setprio(0);
    __builtin_amdgcn_s_barrier();
    MEMFENCE;
    // ---------------- phase 1: k-half 1 ----------------
#pragma unroll
    for (int m = 0; m < 4; ++m)
      af[m] = *(const bf16x8*)&sA[buf][1][(wm * 64 + m * 16 + lr) * 32 + kofs];
#pragma unroll
    for (int n = 0; n < 4; ++n)
      bv[n] = *(const bf16x8*)&sB[buf][1][(wn * 64 + n * 16 + lr) * 32 + kofs];
    if (t + 2 < nkt) {                      // stage k-half0 of tile t+2 -> this buf
      stageA(buf, t + 2, 0);
      stageB(buf, t + 2, 0);
    }
    if (t + 1 < nkt) {
      if (t + 2 < nkt) asm volatile("s_waitcnt vmcnt(6)" ::: "memory");
      else             asm volatile("s_waitcnt vmcnt(3)" ::: "memory");
      __builtin_amdgcn_s_barrier();
    }
    asm volatile("s_waitcnt lgkmcnt(0)" ::: "memory");
    __builtin_amdgcn_sched_barrier(0);
    __builtin_amdgcn_s_setprio(1);
#pragma unroll
    for (int m = 0; m < 4; ++m)
#pragma unroll
      for (int n = 0; n < 4; ++n)
        acc[m][n] = __builtin_amdgcn_mfma_f32_16x16x32_bf16(af[m], bv[n], acc[m][n], 0, 0, 0);
    __builtin_amdgcn_s_setprio(0);
    if (t + 1 < nkt) {
      __builtin_amdgcn_s_barrier();
      MEMFENCE;
    }
  }

  // epilogue: D row=(lane>>4)*4+i, col=lane&15 within each 16x16 fragment
#pragma unroll
  for (int m = 0; m < 4; ++m) {
#pragma unroll
    for (int i = 0; i < 4; ++i) {
      int r = m0 + wm * 64 + m * 16 + kg * 4 + i;
#pragma unroll
      for (int n = 0; n < 4; ++n) {
        int c = n0 + wn * 64 + n * 16 + lr;
        float v = acc[m][n][i];
        if (MODE == 0) {
          const float* bias = (z == 0) ? bias0 : (z == 1) ? bias1 : bias2;
          ((__bf16*)Out)[(size_t)z * sOz + (size_t)r * ldo + c] = (__bf16)(v + bias[c]);
        } else if (MODE == 1) {
          ((float*)Out)[(size_t)z * sOz + (size_t)r * ldo + c] = v * scale;
        } else {
          ((float*)Out)[(size_t)z * sOz + (size_t)r * ldo + c] = v;
        }
      }
    }
  }
}

// ---------------------------------------------------------------------------
extern "C" void kernel_launch(void* const* d_in, const int* in_sizes, int n_in,
                              void* d_out, int out_size, void* d_ws, size_t ws_size,
                              hipStream_t stream) {
  const float* x  = (const float*)d_in[0];
  const float* Wk = (const float*)d_in[1];
  const float* Wq = (const float*)d_in[2];
  const float* Wv = (const float*)d_in[3];
  const float* bk = (const float*)d_in[4];
  const float* bq = (const float*)d_in[5];
  const float* bv = (const float*)d_in[6];
  float* out = (float*)d_out;

  const int B = 4, T = 2048, C = 1024;
  const int M = B * T;  // 8192

  char* ws = (char*)d_ws;
  __bf16* x_bf = (__bf16*)ws;                    // 16 MB
  __bf16* w_bf = (__bf16*)(ws + 16777216);       // 6 MB
  __bf16* kqv  = (__bf16*)(ws + 23068672);       // 48 MB
  __bf16* vt   = (__bf16*)(ws + 73400320);       // 16 MB
  float*  sc   = (float*)(ws + 90177536);        // 64 MB; attn aliased bf16 in-place

  cast_k<<<(M * C / 4 + 255) / 256, 256, 0, stream>>>(x, x_bf, M * C / 4);
  cast_k<<<(C * C / 4 + 255) / 256, 256, 0, stream>>>(Wk, w_bf, C * C / 4);
  cast_k<<<(C * C / 4 + 255) / 256, 256, 0, stream>>>(Wq, w_bf + C * C, C * C / 4);
  cast_k<<<(C * C / 4 + 255) / 256, 256, 0, stream>>>(Wv, w_bf + 2 * C * C, C * C / 4);

  // QKV projection: [8192,1024] x [1024,1024]^T, z = {K,Q,V}
  gemm_pipe<0><<<dim3(M / 256, C / 128, 3), 512, 0, stream>>>(
      x_bf, w_bf, kqv, C, C, C, C / 64, bk, bq, bv, 1.f,
      (size_t)0, (size_t)C * C, (size_t)M * C);

  // V transpose -> Vt[b][c][s]
  transpose_k<<<dim3(T / 32, C / 32, B), dim3(32, 8), 0, stream>>>(
      kqv + 2 * (size_t)M * C, vt, T, C);

  // scores = K @ Q^T / sqrt(C), per batch; skip fully-masked tiles
  gemm_pipe<1><<<dim3(T / 256, T / 128, B), 512, 0, stream>>>(
      kqv, kqv + (size_t)M * C, sc, C, C, T, C / 64, nullptr, nullptr, nullptr,
      0.03125f, (size_t)T * C, (size_t)T * C, (size_t)T * T);

  // causal softmax, scores(f32) -> attn(bf16) in place
  softmax_causal_k<<<B * T, 256, 0, stream>>>(sc, T);

  // out = attn @ V  (attn bf16 rows, stride 2T; B = Vt[n=c][k=s])
  gemm_pipe<2><<<dim3(T / 256, C / 128, B), 512, 0, stream>>>(
      (const __bf16*)sc, vt, out, 2 * T, T, C, T / 64, nullptr, nullptr, nullptr,
      1.f, (size_t)T * 2 * T, (size_t)C * T, (size_t)T * C);
}

// Round 3
// 213.234 us; speedup vs baseline: 1.0068x; 1.0052x over previous
//
#include <hip/hip_runtime.h>

typedef __bf16 bf16x8 __attribute__((ext_vector_type(8)));
typedef __bf16 bf16x4v __attribute__((ext_vector_type(4)));
typedef float f32x4 __attribute__((ext_vector_type(4)));

typedef const void __attribute__((address_space(1)))* gas_ptr;
typedef void __attribute__((address_space(3)))* las_ptr;

__device__ __forceinline__ void gload16(const __bf16* g, __bf16* lds) {
  __builtin_amdgcn_global_load_lds((gas_ptr)g, (las_ptr)lds, 16, 0, 0);
}

// ---------------------------------------------------------------------------
__global__ __launch_bounds__(256) void cast_k(const float* __restrict__ in,
                                              __bf16* __restrict__ out, int n4) {
  int i = blockIdx.x * 256 + threadIdx.x;
  if (i >= n4) return;
  float4 v = ((const float4*)in)[i];
  bf16x4v o = { (__bf16)v.x, (__bf16)v.y, (__bf16)v.z, (__bf16)v.w };
  ((bf16x4v*)out)[i] = o;
}

// ---------------------------------------------------------------------------
__global__ void transpose_k(const __bf16* __restrict__ V, __bf16* __restrict__ Vt,
                            int T, int C) {
  __shared__ __bf16 tile[32][33];
  int b = blockIdx.z;
  int s0 = blockIdx.x * 32, c0 = blockIdx.y * 32;
  const __bf16* Vb = V + (size_t)b * T * C;
  __bf16* Vtb = Vt + (size_t)b * C * T;
  int tx = threadIdx.x, ty = threadIdx.y;  // 32 x 8
  for (int i = ty; i < 32; i += 8) tile[i][tx] = Vb[(size_t)(s0 + i) * C + c0 + tx];
  __syncthreads();
  for (int i = ty; i < 32; i += 8) Vtb[(size_t)(c0 + i) * T + s0 + tx] = tile[tx][i];
}

// ---------------------------------------------------------------------------
__global__ __launch_bounds__(256) void softmax_causal_k(float* __restrict__ scores, int T) {
  const int row = blockIdx.x;  // b*T + t
  const int t = row & (T - 1);
  float* srow = scores + (size_t)row * T;
  __bf16* arow = (__bf16*)srow;
  __shared__ float rb[2048];
  __shared__ float redmax[4];
  __shared__ float redsum[4];
  const int tid = threadIdx.x, lane = tid & 63, wave = tid >> 6;
  for (int s = tid; s < T; s += 256) rb[s] = (s <= t) ? srow[s] : -3.0e38f;
  __syncthreads();
  float lmax = -3.0e38f;
  for (int s = tid; s < T; s += 256) lmax = fmaxf(lmax, rb[s]);
#pragma unroll
  for (int off = 32; off; off >>= 1) lmax = fmaxf(lmax, __shfl_down(lmax, off));
  if (lane == 0) redmax[wave] = lmax;
  __syncthreads();
  float gmax = fmaxf(fmaxf(redmax[0], redmax[1]), fmaxf(redmax[2], redmax[3]));
  float lsum = 0.f;
  for (int s = tid; s < T; s += 256) {
    float e = (s <= t) ? __expf(rb[s] - gmax) : 0.f;
    rb[s] = e;
    lsum += e;
  }
#pragma unroll
  for (int off = 32; off; off >>= 1) lsum += __shfl_down(lsum, off);
  if (lane == 0) redsum[wave] = lsum;
  __syncthreads();
  float inv = 1.f / (redsum[0] + redsum[1] + redsum[2] + redsum[3]);
  for (int s = tid; s < T; s += 256) arow[s] = (__bf16)(rb[s] * inv);
}

// ---------------------------------------------------------------------------
// m201-style 8-phase NT GEMM. C[m,n] = sum_k A[m,k]*B[n,k].
// BM=BN=256, BK=64, 8 waves (2M x 4N), wave tile 128x64, acc[8][4].
// LDS 128 KiB: sA/sB [2 dbuf][256 rows][64 k] bf16, XOR-swizzled 16B chunks
// (phys = chunk ^ (row&7)), same involution at gload source and ds_read.
// Per K-tile: 4 phases x {ds_read, stage 1 half-part, barrier, lgkm0, 16 MFMA,
// barrier}; vmcnt(4) once per K-tile. Stage stream during compute of tile t:
// [t+1 A-lo, t+1 A-hi, t+2 B-lo, t+2 B-hi]  (B regions reusable after ph0,
// A regions only after ph3 -> no LDS overwrite race; vmcnt(4) at ph3
// guarantees all of t+1 resident before the next group reads it).
// MODE 0: proj  -> bf16 out + bias (B rows = concat[Wk;Wq;Wv], col>>10 selects)
// MODE 1: scores-> f32 out * scale, skip blocks with by > bx (z = batch)
// MODE 2: PV    -> f32 out, k-tiles causal-limited (z = batch)
#define MMQ(q)                                                                     \
  __builtin_amdgcn_s_setprio(1);                                                   \
  _Pragma("unroll") for (int f = 0; f < 2; ++f)                                    \
  _Pragma("unroll") for (int n = 0; n < 4; ++n)                                    \
  _Pragma("unroll") for (int ks = 0; ks < 2; ++ks)                                 \
      acc[(q)*2 + f][n] = __builtin_amdgcn_mfma_f32_16x16x32_bf16(                 \
          af[f * 2 + ks], bfr[n * 2 + ks], acc[(q)*2 + f][n], 0, 0, 0);            \
  __builtin_amdgcn_s_setprio(0);

template <int MODE>
__global__ __launch_bounds__(512, 2) void gemm8p(
    const __bf16* __restrict__ A, const __bf16* __restrict__ B, void* __restrict__ Out,
    int lda, int ldb, int ldo, int nkt_in,
    const float* __restrict__ bias0, const float* __restrict__ bias1,
    const float* __restrict__ bias2, float scale,
    size_t sAz, size_t sBz, size_t sOz) {
  const int bx = blockIdx.x, by = blockIdx.y, z = blockIdx.z;
  if (MODE == 1 && by > bx) return;  // fully-masked tile
  const int m0 = bx * 256, n0 = by * 256;
  int nkt = nkt_in;
  if (MODE == 2) nkt = min(nkt, bx * 4 + 4);  // causal k-limit (BK=64)

  __shared__ __align__(16) __bf16 sA[2][256 * 64];  // 64 KiB
  __shared__ __align__(16) __bf16 sB[2][256 * 64];  // 64 KiB

  const int tid = threadIdx.x, wid = tid >> 6, lane = tid & 63;
  const int lr = lane & 15, kg = lane >> 4;
  const int wm = wid & 1, wn = wid >> 1;
  const int grow = lane >> 3;                        // staging: row within 8
  const int gcol = ((lane & 7) ^ grow) << 3;         // staging: swizzled k-chunk

  const __bf16* Ab = A + (size_t)z * sAz + (size_t)m0 * lda;
  const __bf16* Bb = B + (size_t)z * sBz + (size_t)n0 * ldb;

  // stage half h (128 rows) of one matrix: 2 x global_load_lds per thread
  auto stageA = [&](int buf, int kt, int h) {
#pragma unroll
    for (int r = 0; r < 2; ++r) {
      int br = h * 128 + r * 64 + wid * 8;           // wave-uniform base row
      gload16(Ab + (size_t)(br + grow) * lda + kt * 64 + gcol, &sA[buf][br * 64]);
    }
  };
  auto stageB = [&](int buf, int kt, int h) {
#pragma unroll
    for (int r = 0; r < 2; ++r) {
      int br = h * 128 + r * 64 + wid * 8;
      gload16(Bb + (size_t)(br + grow) * ldb + kt * 64 + gcol, &sB[buf][br * 64]);
    }
  };
  auto ldA = [&](bf16x8* af, int buf, int q) {
#pragma unroll
    for (int f = 0; f < 2; ++f)
#pragma unroll
      for (int ks = 0; ks < 2; ++ks) {
        int row = wm * 128 + (q * 2 + f) * 16 + lr;
        int phys = ((ks * 4 + kg) ^ (lr & 7)) << 3;
        af[f * 2 + ks] = *(const bf16x8*)&sA[buf][row * 64 + phys];
      }
  };
  auto ldB = [&](bf16x8* bfr, int buf) {
#pragma unroll
    for (int f = 0; f < 4; ++f)
#pragma unroll
      for (int ks = 0; ks < 2; ++ks) {
        int row = wn * 64 + f * 16 + lr;
        int phys = ((ks * 4 + kg) ^ (lr & 7)) << 3;
        bfr[f * 2 + ks] = *(const bf16x8*)&sB[buf][row * 64 + phys];
      }
  };

  f32x4 acc[8][4];
  const f32x4 zero = {0.f, 0.f, 0.f, 0.f};
#pragma unroll
  for (int m = 0; m < 8; ++m)
#pragma unroll
    for (int n = 0; n < 4; ++n) acc[m][n] = zero;

  // prologue: all of tile 0, then B of tile 1; vmcnt(4) -> tile 0 resident
  stageB(0, 0, 0); stageB(0, 0, 1);
  stageA(0, 0, 0); stageA(0, 0, 1);
  if (nkt > 1) { stageB(1, 1, 0); stageB(1, 1, 1); }
  if (nkt > 1) asm volatile("s_waitcnt vmcnt(4)" ::: "memory");
  else         asm volatile("s_waitcnt vmcnt(0)" ::: "memory");
  __builtin_amdgcn_s_barrier();

  for (int t = 0; t < nkt; ++t) {
    const int buf = t & 1;
    bf16x8 bfr[8], af[4];
    // ---- phase 0: B(all) + A(q0); stage t+1 A-lo -> buf^1 ----
    ldB(bfr, buf);
    ldA(af, buf, 0);
    if (t + 1 < nkt) stageA(buf ^ 1, t + 1, 0);
    __builtin_amdgcn_s_barrier();
    asm volatile("s_waitcnt lgkmcnt(0)" ::: "memory");
    __builtin_amdgcn_sched_barrier(0);
    MMQ(0)
    __builtin_amdgcn_s_barrier();
    // ---- phase 1: A(q1); stage t+1 A-hi -> buf^1 ----
    ldA(af, buf, 1);
    if (t + 1 < nkt) stageA(buf ^ 1, t + 1, 1);
    __builtin_amdgcn_s_barrier();
    asm volatile("s_waitcnt lgkmcnt(0)" ::: "memory");
    __builtin_amdgcn_sched_barrier(0);
    MMQ(1)
    __builtin_amdgcn_s_barrier();
    // ---- phase 2: A(q2); stage t+2 B-lo -> buf (B reads retired in ph0) ----
    ldA(af, buf, 2);
    if (t + 2 < nkt) stageB(buf, t + 2, 0);
    __builtin_amdgcn_s_barrier();
    asm volatile("s_waitcnt lgkmcnt(0)" ::: "memory");
    __builtin_amdgcn_sched_barrier(0);
    MMQ(2)
    __builtin_amdgcn_s_barrier();
    // ---- phase 3: A(q3); stage t+2 B-hi; vmcnt(4) -> t+1 fully resident ----
    ldA(af, buf, 3);
    if (t + 2 < nkt) stageB(buf, t + 2, 1);
    if (t + 2 < nkt) asm volatile("s_waitcnt vmcnt(4)" ::: "memory");
    else             asm volatile("s_waitcnt vmcnt(0)" ::: "memory");
    __builtin_amdgcn_s_barrier();
    asm volatile("s_waitcnt lgkmcnt(0)" ::: "memory");
    __builtin_amdgcn_sched_barrier(0);
    MMQ(3)
    __builtin_amdgcn_s_barrier();
  }

  // epilogue: D row=(lane>>4)*4+i, col=lane&15 within each 16x16 fragment
#pragma unroll
  for (int mf = 0; mf < 8; ++mf) {
#pragma unroll
    for (int i = 0; i < 4; ++i) {
      int r = m0 + wm * 128 + mf * 16 + kg * 4 + i;
#pragma unroll
      for (int nf = 0; nf < 4; ++nf) {
        int c = n0 + wn * 64 + nf * 16 + lr;
        float v = acc[mf][nf][i];
        if (MODE == 0) {
          int zc = c >> 10, cc = c & 1023;
          const float* bias = (zc == 0) ? bias0 : (zc == 1) ? bias1 : bias2;
          ((__bf16*)Out)[(size_t)zc * sOz + (size_t)r * ldo + cc] = (__bf16)(v + bias[cc]);
        } else if (MODE == 1) {
          ((float*)Out)[(size_t)z * sOz + (size_t)r * ldo + c] = v * scale;
        } else {
          ((float*)Out)[(size_t)z * sOz + (size_t)r * ldo + c] = v;
        }
      }
    }
  }
}

// ---------------------------------------------------------------------------
extern "C" void kernel_launch(void* const* d_in, const int* in_sizes, int n_in,
                              void* d_out, int out_size, void* d_ws, size_t ws_size,
                              hipStream_t stream) {
  const float* x  = (const float*)d_in[0];
  const float* Wk = (const float*)d_in[1];
  const float* Wq = (const float*)d_in[2];
  const float* Wv = (const float*)d_in[3];
  const float* bk = (const float*)d_in[4];
  const float* bq = (const float*)d_in[5];
  const float* bv = (const float*)d_in[6];
  float* out = (float*)d_out;

  const int B = 4, T = 2048, C = 1024;
  const int M = B * T;  // 8192

  char* ws = (char*)d_ws;
  __bf16* x_bf = (__bf16*)ws;                    // 16 MB
  __bf16* w_bf = (__bf16*)(ws + 16777216);       // 6 MB  (Wk|Wq|Wv concat, 3072x1024)
  __bf16* kqv  = (__bf16*)(ws + 23068672);       // 48 MB (K|Q|V, each [M][C])
  __bf16* vt   = (__bf16*)(ws + 73400320);       // 16 MB (Vt [B][C][T])
  float*  sc   = (float*)(ws + 90177536);        // 64 MB scores; attn bf16 in-place

  cast_k<<<(M * C / 4 + 255) / 256, 256, 0, stream>>>(x, x_bf, M * C / 4);
  cast_k<<<(C * C / 4 + 255) / 256, 256, 0, stream>>>(Wk, w_bf, C * C / 4);
  cast_k<<<(C * C / 4 + 255) / 256, 256, 0, stream>>>(Wq, w_bf + C * C, C * C / 4);
  cast_k<<<(C * C / 4 + 255) / 256, 256, 0, stream>>>(Wv, w_bf + 2 * C * C, C * C / 4);

  // QKV projection as ONE GEMM: [8192,1024] x [3072,1024]^T
  gemm8p<0><<<dim3(M / 256, 3 * C / 256, 1), 512, 0, stream>>>(
      x_bf, w_bf, kqv, C, C, C, C / 64, bk, bq, bv, 1.f,
      (size_t)0, (size_t)0, (size_t)M * C);

  // V transpose -> Vt[b][c][s]
  transpose_k<<<dim3(T / 32, C / 32, B), dim3(32, 8), 0, stream>>>(
      kqv + 2 * (size_t)M * C, vt, T, C);

  // scores = K @ Q^T / sqrt(C), per batch; skip fully-masked tiles
  gemm8p<1><<<dim3(T / 256, T / 256, B), 512, 0, stream>>>(
      kqv, kqv + (size_t)M * C, sc, C, C, T, C / 64, nullptr, nullptr, nullptr,
      0.03125f, (size_t)T * C, (size_t)T * C, (size_t)T * T);

  // causal softmax, scores(f32) -> attn(bf16) in place
  softmax_causal_k<<<B * T, 256, 0, stream>>>(sc, T);

  // out = attn @ V  (attn bf16 rows, stride 2T; B = Vt[c][s])
  gemm8p<2><<<dim3(T / 256, C / 256, B), 512, 0, stream>>>(
      (const __bf16*)sc, vt, out, 2 * T, T, C, T / 64, nullptr, nullptr, nullptr,
      1.f, (size_t)T * 2 * T, (size_t)C * T, (size_t)T * C);
}

// Round 4
// 210.149 us; speedup vs baseline: 1.0216x; 1.0147x over previous
//
#include <hip/hip_runtime.h>

typedef __bf16 bf16x8 __attribute__((ext_vector_type(8)));
typedef __bf16 bf16x4v __attribute__((ext_vector_type(4)));
typedef float f32x4 __attribute__((ext_vector_type(4)));

typedef const void __attribute__((address_space(1)))* gas_ptr;
typedef void __attribute__((address_space(3)))* las_ptr;

__device__ __forceinline__ void gload16(const __bf16* g, __bf16* lds) {
  __builtin_amdgcn_global_load_lds((gas_ptr)g, (las_ptr)lds, 16, 0, 0);
}

// ---------------------------------------------------------------------------
__global__ __launch_bounds__(256) void cast_k(const float* __restrict__ in,
                                              __bf16* __restrict__ out, int n4) {
  int i = blockIdx.x * 256 + threadIdx.x;
  if (i >= n4) return;
  float4 v = ((const float4*)in)[i];
  bf16x4v o = { (__bf16)v.x, (__bf16)v.y, (__bf16)v.z, (__bf16)v.w };
  ((bf16x4v*)out)[i] = o;
}

// weights: 3 separate src pointers, z selects
__global__ __launch_bounds__(256) void cast_w_k(const float* __restrict__ w0,
                                                const float* __restrict__ w1,
                                                const float* __restrict__ w2,
                                                __bf16* __restrict__ out, int n4) {
  int z = blockIdx.y;
  const float* in = (z == 0) ? w0 : (z == 1) ? w1 : w2;
  int i = blockIdx.x * 256 + threadIdx.x;
  if (i >= n4) return;
  float4 v = ((const float4*)in)[i];
  bf16x4v o = { (__bf16)v.x, (__bf16)v.y, (__bf16)v.z, (__bf16)v.w };
  ((bf16x4v*)(out + (size_t)z * n4 * 4))[i] = o;
}

// ---------------------------------------------------------------------------
__global__ void transpose_k(const __bf16* __restrict__ V, __bf16* __restrict__ Vt,
                            int T, int C) {
  __shared__ __bf16 tile[32][33];
  int b = blockIdx.z;
  int s0 = blockIdx.x * 32, c0 = blockIdx.y * 32;
  const __bf16* Vb = V + (size_t)b * T * C;
  __bf16* Vtb = Vt + (size_t)b * C * T;
  int tx = threadIdx.x, ty = threadIdx.y;  // 32 x 8
  for (int i = ty; i < 32; i += 8) tile[i][tx] = Vb[(size_t)(s0 + i) * C + c0 + tx];
  __syncthreads();
  for (int i = ty; i < 32; i += 8) Vtb[(size_t)(c0 + i) * T + s0 + tx] = tile[tx][i];
}

// ---------------------------------------------------------------------------
__global__ __launch_bounds__(256) void softmax_causal_k(float* __restrict__ scores, int T) {
  const int row = blockIdx.x;  // b*T + t
  const int t = row & (T - 1);
  float* srow = scores + (size_t)row * T;
  __bf16* arow = (__bf16*)srow;
  __shared__ float rb[2048];
  __shared__ float redmax[4];
  __shared__ float redsum[4];
  const int tid = threadIdx.x, lane = tid & 63, wave = tid >> 6;
  for (int s = tid; s < T; s += 256) rb[s] = (s <= t) ? srow[s] : -3.0e38f;
  __syncthreads();
  float lmax = -3.0e38f;
  for (int s = tid; s < T; s += 256) lmax = fmaxf(lmax, rb[s]);
#pragma unroll
  for (int off = 32; off; off >>= 1) lmax = fmaxf(lmax, __shfl_down(lmax, off));
  if (lane == 0) redmax[wave] = lmax;
  __syncthreads();
  float gmax = fmaxf(fmaxf(redmax[0], redmax[1]), fmaxf(redmax[2], redmax[3]));
  float lsum = 0.f;
  for (int s = tid; s < T; s += 256) {
    float e = (s <= t) ? __expf(rb[s] - gmax) : 0.f;
    rb[s] = e;
    lsum += e;
  }
#pragma unroll
  for (int off = 32; off; off >>= 1) lsum += __shfl_down(lsum, off);
  if (lane == 0) redsum[wave] = lsum;
  __syncthreads();
  float inv = 1.f / (redsum[0] + redsum[1] + redsum[2] + redsum[3]);
  for (int s = tid; s < T; s += 256) arow[s] = (__bf16)(rb[s] * inv);
}

// ---------------------------------------------------------------------------
// m201-faithful 8-phase NT GEMM. C[m,n] = sum_k A[m,k]*B[n,k].
// BM=BN=256, BK=64, 8 waves 2M x 4N with ROW-INTERLEAVED wave tiles:
// wave (wm,wn) owns row frags  q*64 + f*32 + wm*16  (q=0..3 phase, f=0..1)
// and col frags wn*64 + nf*16. acc[8][4] (mf = q*2+f).
// Key property: phase q reads ONLY global row-quadrant q of sA -> region
// retires at end of phase q -> deep stage-ahead is race-free:
//   ph0: stage A-hi(t+1)   [A-hi(t-1) retired t-1.ph3]
//   ph1: stage B-lo(t+2)   [B(t) retired ph0]
//   ph2: stage B-hi(t+2)
//   ph3: stage A-lo(t+2)   [A-lo(t) retired ph1]; vmcnt(6) gates tile t+1
// vmcnt(6) = leave newest 3 half-stages (6 loads) in flight; A(t+1) covered
// 3.5+ phases, B(t+2) 6-7 phases. Never drains to 0 in steady state.
// MODE 0: proj  -> bf16 out + bias (B rows = concat[Wk;Wq;Wv], col>>10 selects)
// MODE 1: scores-> f32 out * scale, skip blocks with by > bx (z = batch)
// MODE 2: PV    -> f32 out, k-tiles causal-limited (z = batch)
#define MMQ(q)                                                                     \
  __builtin_amdgcn_s_setprio(1);                                                   \
  _Pragma("unroll") for (int f = 0; f < 2; ++f)                                    \
  _Pragma("unroll") for (int n = 0; n < 4; ++n)                                    \
  _Pragma("unroll") for (int ks = 0; ks < 2; ++ks)                                 \
      acc[(q)*2 + f][n] = __builtin_amdgcn_mfma_f32_16x16x32_bf16(                 \
          af[f * 2 + ks], bfr[n * 2 + ks], acc[(q)*2 + f][n], 0, 0, 0);            \
  __builtin_amdgcn_s_setprio(0);

template <int MODE>
__global__ __launch_bounds__(512, 2) void gemm8p(
    const __bf16* __restrict__ A, const __bf16* __restrict__ B, void* __restrict__ Out,
    int lda, int ldb, int ldo, int nkt_in,
    const float* __restrict__ bias0, const float* __restrict__ bias1,
    const float* __restrict__ bias2, float scale,
    size_t sAz, size_t sBz, size_t sOz) {
  const int bx = blockIdx.x, by = blockIdx.y, z = blockIdx.z;
  if (MODE == 1 && by > bx) return;  // fully-masked tile
  const int m0 = bx * 256, n0 = by * 256;
  int nkt = nkt_in;
  if (MODE == 2) nkt = min(nkt, bx * 4 + 4);  // causal k-limit (BK=64)

  __shared__ __align__(16) __bf16 sA[2][256 * 64];  // 64 KiB
  __shared__ __align__(16) __bf16 sB[2][256 * 64];  // 64 KiB

  const int tid = threadIdx.x, wid = tid >> 6, lane = tid & 63;
  const int lr = lane & 15, kg = lane >> 4;
  const int wm = wid & 1, wn = wid >> 1;
  const int grow = lane >> 3;                 // staging: row within 8
  const int gcol = ((lane & 7) ^ grow) << 3;  // staging: swizzled k-chunk

  const __bf16* Ab = A + (size_t)z * sAz + (size_t)m0 * lda;
  const __bf16* Bb = B + (size_t)z * sBz + (size_t)n0 * ldb;

  // stage half h (128 rows) of one matrix: 2 x global_load_lds per thread
  auto stageA = [&](int buf, int kt, int h) {
#pragma unroll
    for (int r = 0; r < 2; ++r) {
      int br = h * 128 + r * 64 + wid * 8;  // wave-uniform base row
      gload16(Ab + (size_t)(br + grow) * lda + kt * 64 + gcol, &sA[buf][br * 64]);
    }
  };
  auto stageB = [&](int buf, int kt, int h) {
#pragma unroll
    for (int r = 0; r < 2; ++r) {
      int br = h * 128 + r * 64 + wid * 8;
      gload16(Bb + (size_t)(br + grow) * ldb + kt * 64 + gcol, &sB[buf][br * 64]);
    }
  };
  // phase-q A frags: rows q*64 + f*32 + wm*16 + lr  (region = quadrant q only)
  auto ldA = [&](bf16x8* af, int buf, int q) {
#pragma unroll
    for (int f = 0; f < 2; ++f)
#pragma unroll
      for (int ks = 0; ks < 2; ++ks) {
        int row = q * 64 + f * 32 + wm * 16 + lr;
        int phys = ((ks * 4 + kg) ^ (lr & 7)) << 3;
        af[f * 2 + ks] = *(const bf16x8*)&sA[buf][row * 64 + phys];
      }
  };
  auto ldB = [&](bf16x8* bfr, int buf) {
#pragma unroll
    for (int f = 0; f < 4; ++f)
#pragma unroll
      for (int ks = 0; ks < 2; ++ks) {
        int row = wn * 64 + f * 16 + lr;
        int phys = ((ks * 4 + kg) ^ (lr & 7)) << 3;
        bfr[f * 2 + ks] = *(const bf16x8*)&sB[buf][row * 64 + phys];
      }
  };

  f32x4 acc[8][4];
  const f32x4 zero = {0.f, 0.f, 0.f, 0.f};
#pragma unroll
  for (int m = 0; m < 8; ++m)
#pragma unroll
    for (int n = 0; n < 4; ++n) acc[m][n] = zero;

  // prologue: tile0 (oldest), then B(1), A-lo(1) — steady-state pre-issue set
  stageA(0, 0, 0); stageA(0, 0, 1);
  stageB(0, 0, 0); stageB(0, 0, 1);
  if (nkt > 1) { stageB(1, 1, 0); stageB(1, 1, 1); stageA(1, 1, 0); }
  if (nkt > 1) asm volatile("s_waitcnt vmcnt(6)" ::: "memory");
  else         asm volatile("s_waitcnt vmcnt(0)" ::: "memory");
  __builtin_amdgcn_s_barrier();

  for (int t = 0; t < nkt; ++t) {
    const int buf = t & 1;
    bf16x8 bfr[8], af[4];
    // ---- phase 0: B(all) + A(q0); stage A-hi(t+1) -> buf^1 ----
    ldB(bfr, buf);
    ldA(af, buf, 0);
    if (t + 1 < nkt) stageA(buf ^ 1, t + 1, 1);
    __builtin_amdgcn_s_barrier();
    asm volatile("s_waitcnt lgkmcnt(0)" ::: "memory");
    __builtin_amdgcn_sched_barrier(0);
    MMQ(0)
    __builtin_amdgcn_s_barrier();
    // ---- phase 1: A(q1); stage B-lo(t+2) -> buf (B(t) retired ph0) ----
    ldA(af, buf, 1);
    if (t + 2 < nkt) stageB(buf, t + 2, 0);
    __builtin_amdgcn_s_barrier();
    asm volatile("s_waitcnt lgkmcnt(0)" ::: "memory");
    __builtin_amdgcn_sched_barrier(0);
    MMQ(1)
    __builtin_amdgcn_s_barrier();
    // ---- phase 2: A(q2); stage B-hi(t+2) -> buf ----
    ldA(af, buf, 2);
    if (t + 2 < nkt) stageB(buf, t + 2, 1);
    __builtin_amdgcn_s_barrier();
    asm volatile("s_waitcnt lgkmcnt(0)" ::: "memory");
    __builtin_amdgcn_sched_barrier(0);
    MMQ(2)
    __builtin_amdgcn_s_barrier();
    // ---- phase 3: A(q3); stage A-lo(t+2) (A-lo(t) retired ph1); gate t+1 ----
    ldA(af, buf, 3);
    if (t + 2 < nkt) {
      stageA(buf, t + 2, 0);
      asm volatile("s_waitcnt vmcnt(6)" ::: "memory");
    } else if (t + 1 < nkt) {
      asm volatile("s_waitcnt vmcnt(0)" ::: "memory");
    }
    __builtin_amdgcn_s_barrier();
    asm volatile("s_waitcnt lgkmcnt(0)" ::: "memory");
    __builtin_amdgcn_sched_barrier(0);
    MMQ(3)
    __builtin_amdgcn_s_barrier();
  }

  // epilogue: r = m0 + q*64 + f*32 + wm*16 + kg*4 + i  (mf = q*2+f)
#pragma unroll
  for (int mf = 0; mf < 8; ++mf) {
#pragma unroll
    for (int i = 0; i < 4; ++i) {
      int r = m0 + (mf >> 1) * 64 + (mf & 1) * 32 + wm * 16 + kg * 4 + i;
#pragma unroll
      for (int nf = 0; nf < 4; ++nf) {
        int c = n0 + wn * 64 + nf * 16 + lr;
        float v = acc[mf][nf][i];
        if (MODE == 0) {
          int zc = c >> 10, cc = c & 1023;
          const float* bias = (zc == 0) ? bias0 : (zc == 1) ? bias1 : bias2;
          ((__bf16*)Out)[(size_t)zc * sOz + (size_t)r * ldo + cc] = (__bf16)(v + bias[cc]);
        } else if (MODE == 1) {
          ((float*)Out)[(size_t)z * sOz + (size_t)r * ldo + c] = v * scale;
        } else {
          ((float*)Out)[(size_t)z * sOz + (size_t)r * ldo + c] = v;
        }
      }
    }
  }
}

// ---------------------------------------------------------------------------
extern "C" void kernel_launch(void* const* d_in, const int* in_sizes, int n_in,
                              void* d_out, int out_size, void* d_ws, size_t ws_size,
                              hipStream_t stream) {
  const float* x  = (const float*)d_in[0];
  const float* Wk = (const float*)d_in[1];
  const float* Wq = (const float*)d_in[2];
  const float* Wv = (const float*)d_in[3];
  const float* bk = (const float*)d_in[4];
  const float* bq = (const float*)d_in[5];
  const float* bv = (const float*)d_in[6];
  float* out = (float*)d_out;

  const int B = 4, T = 2048, C = 1024;
  const int M = B * T;  // 8192

  char* ws = (char*)d_ws;
  __bf16* x_bf = (__bf16*)ws;                    // 16 MB
  __bf16* w_bf = (__bf16*)(ws + 16777216);       // 6 MB  (Wk|Wq|Wv concat, 3072x1024)
  __bf16* kqv  = (__bf16*)(ws + 23068672);       // 48 MB (K|Q|V, each [M][C])
  __bf16* vt   = (__bf16*)(ws + 73400320);       // 16 MB (Vt [B][C][T])
  float*  sc   = (float*)(ws + 90177536);        // 64 MB scores; attn bf16 in-place

  cast_k<<<(M * C / 4 + 255) / 256, 256, 0, stream>>>(x, x_bf, M * C / 4);
  cast_w_k<<<dim3((C * C / 4 + 255) / 256, 3), 256, 0, stream>>>(
      Wk, Wq, Wv, w_bf, C * C / 4);

  // QKV projection as ONE GEMM: [8192,1024] x [3072,1024]^T
  gemm8p<0><<<dim3(M / 256, 3 * C / 256, 1), 512, 0, stream>>>(
      x_bf, w_bf, kqv, C, C, C, C / 64, bk, bq, bv, 1.f,
      (size_t)0, (size_t)0, (size_t)M * C);

  // V transpose -> Vt[b][c][s]
  transpose_k<<<dim3(T / 32, C / 32, B), dim3(32, 8), 0, stream>>>(
      kqv + 2 * (size_t)M * C, vt, T, C);

  // scores = K @ Q^T / sqrt(C), per batch; skip fully-masked tiles
  gemm8p<1><<<dim3(T / 256, T / 256, B), 512, 0, stream>>>(
      kqv, kqv + (size_t)M * C, sc, C, C, T, C / 64, nullptr, nullptr, nullptr,
      0.03125f, (size_t)T * C, (size_t)T * C, (size_t)T * T);

  // causal softmax, scores(f32) -> attn(bf16) in place
  softmax_causal_k<<<B * T, 256, 0, stream>>>(sc, T);

  // out = attn @ V  (attn bf16 rows, stride 2T; B = Vt[c][s])
  gemm8p<2><<<dim3(T / 256, C / 256, B), 512, 0, stream>>>(
      (const __bf16*)sc, vt, out, 2 * T, T, C, T / 64, nullptr, nullptr, nullptr,
      1.f, (size_t)T * 2 * T, (size_t)C * T, (size_t)T * C);
}

// Round 5
// 206.442 us; speedup vs baseline: 1.0400x; 1.0180x over previous
//
#include <hip/hip_runtime.h>

typedef __bf16 bf16x8 __attribute__((ext_vector_type(8)));
typedef __bf16 bf16x4v __attribute__((ext_vector_type(4)));
typedef float f32x4 __attribute__((ext_vector_type(4)));

typedef const void __attribute__((address_space(1)))* gas_ptr;
typedef void __attribute__((address_space(3)))* las_ptr;

__device__ __forceinline__ void gload16(const __bf16* g, __bf16* lds) {
  __builtin_amdgcn_global_load_lds((gas_ptr)g, (las_ptr)lds, 16, 0, 0);
}

// ---------------------------------------------------------------------------
__global__ __launch_bounds__(256) void cast_k(const float* __restrict__ in,
                                              __bf16* __restrict__ out, int n4) {
  int i = blockIdx.x * 256 + threadIdx.x;
  if (i >= n4) return;
  float4 v = ((const float4*)in)[i];
  bf16x4v o = { (__bf16)v.x, (__bf16)v.y, (__bf16)v.z, (__bf16)v.w };
  ((bf16x4v*)out)[i] = o;
}

__global__ __launch_bounds__(256) void cast_w_k(const float* __restrict__ w0,
                                                const float* __restrict__ w1,
                                                const float* __restrict__ w2,
                                                __bf16* __restrict__ out, int n4) {
  int z = blockIdx.y;
  const float* in = (z == 0) ? w0 : (z == 1) ? w1 : w2;
  int i = blockIdx.x * 256 + threadIdx.x;
  if (i >= n4) return;
  float4 v = ((const float4*)in)[i];
  bf16x4v o = { (__bf16)v.x, (__bf16)v.y, (__bf16)v.z, (__bf16)v.w };
  ((bf16x4v*)(out + (size_t)z * n4 * 4))[i] = o;
}

// ---------------------------------------------------------------------------
__global__ void transpose_k(const __bf16* __restrict__ V, __bf16* __restrict__ Vt,
                            int T, int C) {
  __shared__ __bf16 tile[32][33];
  int b = blockIdx.z;
  int s0 = blockIdx.x * 32, c0 = blockIdx.y * 32;
  const __bf16* Vb = V + (size_t)b * T * C;
  __bf16* Vtb = Vt + (size_t)b * C * T;
  int tx = threadIdx.x, ty = threadIdx.y;  // 32 x 8
  for (int i = ty; i < 32; i += 8) tile[i][tx] = Vb[(size_t)(s0 + i) * C + c0 + tx];
  __syncthreads();
  for (int i = ty; i < 32; i += 8) Vtb[(size_t)(c0 + i) * T + s0 + tx] = tile[tx][i];
}

// ---------------------------------------------------------------------------
__global__ __launch_bounds__(256) void softmax_causal_k(float* __restrict__ scores, int T) {
  const int row = blockIdx.x;  // b*T + t
  const int t = row & (T - 1);
  float* srow = scores + (size_t)row * T;
  __bf16* arow = (__bf16*)srow;
  __shared__ float rb[2048];
  __shared__ float redmax[4];
  __shared__ float redsum[4];
  const int tid = threadIdx.x, lane = tid & 63, wave = tid >> 6;
  for (int s = tid; s < T; s += 256) rb[s] = (s <= t) ? srow[s] : -3.0e38f;
  __syncthreads();
  float lmax = -3.0e38f;
  for (int s = tid; s < T; s += 256) lmax = fmaxf(lmax, rb[s]);
#pragma unroll
  for (int off = 32; off; off >>= 1) lmax = fmaxf(lmax, __shfl_down(lmax, off));
  if (lane == 0) redmax[wave] = lmax;
  __syncthreads();
  float gmax = fmaxf(fmaxf(redmax[0], redmax[1]), fmaxf(redmax[2], redmax[3]));
  float lsum = 0.f;
  for (int s = tid; s < T; s += 256) {
    float e = (s <= t) ? __expf(rb[s] - gmax) : 0.f;
    rb[s] = e;
    lsum += e;
  }
#pragma unroll
  for (int off = 32; off; off >>= 1) lsum += __shfl_down(lsum, off);
  if (lane == 0) redsum[wave] = lsum;
  __syncthreads();
  float inv = 1.f / (redsum[0] + redsum[1] + redsum[2] + redsum[3]);
  for (int s = tid; s < T; s += 256) arow[s] = (__bf16)(rb[s] * inv);
}

// ---------------------------------------------------------------------------
// Read-ahead pipelined NT GEMM. C[m,n] = sum_k A[m,k]*B[n,k].
// BM=256, BN=128, BK=64 as two 32-k phases. 8 waves (4m x 2n), wave 64x64,
// acc[4][4]. LDS 96 KiB: sA/sB[2 dbuf][2 khalf][rows*32], linear (no swizzle:
// wave b128 reads cover a contiguous 1 KB block = LDS-throughput floor).
// Per phase: {issue NEXT phase's 8 ds_reads | issue 1 stage unit (3 gloads) |
// lgkmcnt(8) (retires PREV phase reads; this phase's overlap the MFMA) |
// sched_barrier | setprio(1) 16 MFMA setprio(0) | vmcnt(3) | s_barrier}.
// Stage stream: t.h0 stages (t+1,k1); t.h1 stages (t+2,k0). vmcnt(3) before
// each barrier retires the stage issued 2 phases earlier = exactly the region
// the NEXT phase reads (per-wave vmcnt => each wave retires its own stage
// contribution before the barrier releasing readers; regions written were
// retired by all readers' lgkm before the preceding barrier -> race-free).
// MODE 0: proj  -> bf16 out + bias (n0>>10 selects K/Q/V slot)
// MODE 1: scores-> f32 out * scale, skip blocks with n0 > m0+255 (z = batch)
// MODE 2: PV    -> f32 out, k-tiles causal-limited (z = batch)
template <int MODE>
__global__ __launch_bounds__(512, 1) void gemm2p(
    const __bf16* __restrict__ A, const __bf16* __restrict__ B, void* __restrict__ Out,
    int lda, int ldb, int ldo, int nkt_in,
    const float* __restrict__ bias0, const float* __restrict__ bias1,
    const float* __restrict__ bias2, float scale,
    size_t sAz, size_t sBz, size_t sOz) {
  const int bx = blockIdx.y, by = blockIdx.x, z = blockIdx.z;  // x = n (fast)
  if (MODE == 1 && by > 2 * bx + 1) return;  // fully-masked tile
  const int m0 = bx * 256, n0 = by * 128;
  int nkt = nkt_in;
  if (MODE == 2) nkt = min(nkt, (bx + 1) * 4);  // causal k-limit (BK=64)

  __shared__ __align__(16) __bf16 sA[2][2][256 * 32];  // 64 KiB
  __shared__ __align__(16) __bf16 sB[2][2][128 * 32];  // 32 KiB

  const int tid = threadIdx.x, wid = tid >> 6, lane = tid & 63;
  const int lr = lane & 15, kg = lane >> 4;
  const int wm = wid & 3, wn = wid >> 2;
  const int srow = lane >> 2;            // staging row within 16
  const int scol = (lane & 3) * 8;       // staging k-chunk (elems)

  const __bf16* Ab = A + (size_t)z * sAz + (size_t)m0 * lda;
  const __bf16* Bb = B + (size_t)z * sBz + (size_t)n0 * ldb;

  // one stage unit = (tile kt, k-half h) of A (2 gloads) + B (1 gload)
  auto stage = [&](int buf, int kt, int h) {
#pragma unroll
    for (int r = 0; r < 2; ++r) {
      int br = r * 128 + wid * 16;  // wave-uniform base row
      gload16(Ab + (size_t)(br + srow) * lda + kt * 64 + h * 32 + scol,
              &sA[buf][h][br * 32]);
    }
    int br = wid * 16;
    gload16(Bb + (size_t)(br + srow) * ldb + kt * 64 + h * 32 + scol,
            &sB[buf][h][br * 32]);
  };
  auto ldA = [&](bf16x8* af, int buf, int h) {
#pragma unroll
    for (int mf = 0; mf < 4; ++mf)
      af[mf] = *(const bf16x8*)&sA[buf][h][(wm * 64 + mf * 16 + lr) * 32 + kg * 8];
  };
  auto ldB = [&](bf16x8* bf, int buf, int h) {
#pragma unroll
    for (int nf = 0; nf < 4; ++nf)
      bf[nf] = *(const bf16x8*)&sB[buf][h][(wn * 64 + nf * 16 + lr) * 32 + kg * 8];
  };

  f32x4 acc[4][4];
  const f32x4 zero = {0.f, 0.f, 0.f, 0.f};
#pragma unroll
  for (int m = 0; m < 4; ++m)
#pragma unroll
    for (int n = 0; n < 4; ++n) acc[m][n] = zero;

  auto MM = [&](bf16x8* af, bf16x8* bf) {
    __builtin_amdgcn_s_setprio(1);
#pragma unroll
    for (int mf = 0; mf < 4; ++mf)
#pragma unroll
      for (int nf = 0; nf < 4; ++nf)
        acc[mf][nf] =
            __builtin_amdgcn_mfma_f32_16x16x32_bf16(af[mf], bf[nf], acc[mf][nf], 0, 0, 0);
    __builtin_amdgcn_s_setprio(0);
  };

  bf16x8 a_cur[4], b_cur[4], a_nxt[4], b_nxt[4];

  // prologue: stage (0,k0),(0,k1)[,(1,k0)]; retire tile-0 halves; pre-read (0,k0)
  stage(0, 0, 0);
  stage(0, 0, 1);
  if (nkt > 1) stage(1, 1, 0);
  if (nkt > 1) asm volatile("s_waitcnt vmcnt(3)" ::: "memory");
  else         asm volatile("s_waitcnt vmcnt(0)" ::: "memory");
  __builtin_amdgcn_s_barrier();
  ldA(a_cur, 0, 0);
  ldB(b_cur, 0, 0);

  for (int t = 0; t < nkt; ++t) {
    const int buf = t & 1;
    // ---- phase h0: MFMA (t,k0); read-ahead (t,k1); stage (t+1,k1) ----
    ldA(a_nxt, buf, 1);
    ldB(b_nxt, buf, 1);
    if (t + 1 < nkt) stage(buf ^ 1, t + 1, 1);
    asm volatile("s_waitcnt lgkmcnt(8)" ::: "memory");
    __builtin_amdgcn_sched_barrier(0);
    MM(a_cur, b_cur);
    if (t + 1 < nkt) asm volatile("s_waitcnt vmcnt(3)" ::: "memory");
    else             asm volatile("s_waitcnt vmcnt(0)" ::: "memory");
    __builtin_amdgcn_s_barrier();
    // ---- phase h1: MFMA (t,k1); read-ahead (t+1,k0); stage (t+2,k0) ----
    if (t + 1 < nkt) {
      ldA(a_cur, buf ^ 1, 0);
      ldB(b_cur, buf ^ 1, 0);
      if (t + 2 < nkt) stage(buf, t + 2, 0);
      asm volatile("s_waitcnt lgkmcnt(8)" ::: "memory");
    } else {
      asm volatile("s_waitcnt lgkmcnt(0)" ::: "memory");
    }
    __builtin_amdgcn_sched_barrier(0);
    MM(a_nxt, b_nxt);
    if (t + 1 < nkt) {
      if (t + 2 < nkt) asm volatile("s_waitcnt vmcnt(3)" ::: "memory");
      else             asm volatile("s_waitcnt vmcnt(0)" ::: "memory");
      __builtin_amdgcn_s_barrier();
    }
  }

  // epilogue: D row=(lane>>4)*4+i, col=lane&15 within each 16x16 fragment
#pragma unroll
  for (int mf = 0; mf < 4; ++mf) {
#pragma unroll
    for (int i = 0; i < 4; ++i) {
      int r = m0 + wm * 64 + mf * 16 + kg * 4 + i;
#pragma unroll
      for (int nf = 0; nf < 4; ++nf) {
        int c = n0 + wn * 64 + nf * 16 + lr;
        float v = acc[mf][nf][i];
        if (MODE == 0) {
          int zc = n0 >> 10, cc = c & 1023;
          const float* bias = (zc == 0) ? bias0 : (zc == 1) ? bias1 : bias2;
          ((__bf16*)Out)[(size_t)zc * sOz + (size_t)r * ldo + cc] = (__bf16)(v + bias[cc]);
        } else if (MODE == 1) {
          ((float*)Out)[(size_t)z * sOz + (size_t)r * ldo + c] = v * scale;
        } else {
          ((float*)Out)[(size_t)z * sOz + (size_t)r * ldo + c] = v;
        }
      }
    }
  }
}

// ---------------------------------------------------------------------------
extern "C" void kernel_launch(void* const* d_in, const int* in_sizes, int n_in,
                              void* d_out, int out_size, void* d_ws, size_t ws_size,
                              hipStream_t stream) {
  const float* x  = (const float*)d_in[0];
  const float* Wk = (const float*)d_in[1];
  const float* Wq = (const float*)d_in[2];
  const float* Wv = (const float*)d_in[3];
  const float* bk = (const float*)d_in[4];
  const float* bq = (const float*)d_in[5];
  const float* bv = (const float*)d_in[6];
  float* out = (float*)d_out;

  const int B = 4, T = 2048, C = 1024;
  const int M = B * T;  // 8192

  char* ws = (char*)d_ws;
  __bf16* x_bf = (__bf16*)ws;                    // 16 MB
  __bf16* w_bf = (__bf16*)(ws + 16777216);       // 6 MB  (Wk|Wq|Wv concat, 3072x1024)
  __bf16* kqv  = (__bf16*)(ws + 23068672);       // 48 MB (K|Q|V, each [M][C])
  __bf16* vt   = (__bf16*)(ws + 73400320);       // 16 MB (Vt [B][C][T])
  float*  sc   = (float*)(ws + 90177536);        // 64 MB scores; attn bf16 in-place

  cast_k<<<(M * C / 4 + 255) / 256, 256, 0, stream>>>(x, x_bf, M * C / 4);
  cast_w_k<<<dim3((C * C / 4 + 255) / 256, 3), 256, 0, stream>>>(
      Wk, Wq, Wv, w_bf, C * C / 4);

  // QKV projection as ONE GEMM: [8192,1024] x [3072,1024]^T  (768 blocks)
  gemm2p<0><<<dim3(3 * C / 128, M / 256, 1), 512, 0, stream>>>(
      x_bf, w_bf, kqv, C, C, C, C / 64, bk, bq, bv, 1.f,
      (size_t)0, (size_t)0, (size_t)M * C);

  // V transpose -> Vt[b][c][s]
  transpose_k<<<dim3(T / 32, C / 32, B), dim3(32, 8), 0, stream>>>(
      kqv + 2 * (size_t)M * C, vt, T, C);

  // scores = K @ Q^T / sqrt(C), per batch; skip fully-masked tiles
  gemm2p<1><<<dim3(T / 128, T / 256, B), 512, 0, stream>>>(
      kqv, kqv + (size_t)M * C, sc, C, C, T, C / 64, nullptr, nullptr, nullptr,
      0.03125f, (size_t)T * C, (size_t)T * C, (size_t)T * T);

  // causal softmax, scores(f32) -> attn(bf16) in place
  softmax_causal_k<<<B * T, 256, 0, stream>>>(sc, T);

  // out = attn @ V  (attn bf16 rows, stride 2T; B = Vt[c][s])
  gemm2p<2><<<dim3(C / 128, T / 256, B), 512, 0, stream>>>(
      (const __bf16*)sc, vt, out, 2 * T, T, C, T / 64, nullptr, nullptr, nullptr,
      1.f, (size_t)T * 2 * T, (size_t)C * T, (size_t)T * C);
}